// Round 14
// baseline (197.427 us; speedup 1.0000x reference)
//
#include <hip/hip_runtime.h>
#include <hip/hip_bf16.h>
#include <hip/hip_cooperative_groups.h>

namespace cg = cooperative_groups;

// Round 14: r12 skeleton (best, 90.66us) + (1) proj/attn fused into ONE
// cooperative kernel (grid.sync between phases; 256 blocks x 1024 thr = 1/CU,
// co-residency guaranteed) and (2) lsum on the MFMA pipe via ones-fragment
// (r10-proven; VALU is the busiest pipe at ~55%, MFMA only ~27%).
// r13's register-only PV REGRESSED (+6.2us) -> reverted to r12's interleaved
// DS round-trip.

#define LSP   576
#define NROW  9216
#define DH    32
#define NW    16              // waves per attn block
#define KPW   (NROW / NW)     // 576 keys per wave
#define NTILE 9               // 9 x 64-key iterations (2 x 32-key subtiles)
#define PSTR  40              // P LDS row stride (ushort): 32 keys + 8 pad
#define QB    36              // queries per attn block (grid = 256 exactly)
#define SZ    ((size_t)NROW * DH)
#define SZP   (SZ + 4096)     // pad: ghost-row reads stay in-bounds

typedef __attribute__((ext_vector_type(8))) short bh8;
typedef __attribute__((ext_vector_type(4))) float f4;

static __device__ __forceinline__ unsigned short f2bf(float x) {
    union { float f; unsigned int i; } w; w.f = x;
    unsigned int u = w.i;
    return (unsigned short)((u + 0x7fffu + ((u >> 16) & 1u)) >> 16);
}
static __device__ __forceinline__ unsigned int pkbf(float a, float b) {
    union { __hip_bfloat162 h2; unsigned int u; } w;
    w.h2 = __float22bfloat162_rn(make_float2(a, b));   // a -> low ushort (RNE)
    return w.u;
}
static __device__ __forceinline__ float fexp2(float x) {
#if __has_builtin(__builtin_amdgcn_exp2f)
    return __builtin_amdgcn_exp2f(x);
#else
    return exp2f(x);
#endif
}

#define MFMA(a, b, c) __builtin_amdgcn_mfma_f32_16x16x32_bf16(a, b, c, 0, 0, 0)

// ---------------- fused proj + attention, cooperative -----------------------
// Phase 1 (proj): block (bg = blk>>4, part = blk&15) computes Q/K/V for its
// 36 spatial columns; Q pre-scaled by 1/sqrt(d)*log2(e); PE fp32; V in 2KB
// permuted key-tiles. Phase 2 (attn): after grid.sync, r12 attention.
__global__ __launch_bounds__(1024, 4) void sa_fused_kernel(
    const float* __restrict__ x,
    const float* __restrict__ wq, const float* __restrict__ wk, const float* __restrict__ wv,
    unsigned short* __restrict__ Qhi, unsigned short* __restrict__ Khi,
    unsigned short* __restrict__ Vt, float* __restrict__ out)
{
    __shared__ __align__(16) unsigned short shm[NW * 48 * PSTR];  // 61.4 KB
    const int t = threadIdx.x;

    // ================= phase 1: projections =================
    {
        float* xs  = (float*)shm;          // 32*40
        float* vt  = xs + 32 * 40;         // 32*37
        float* wqs = vt + 32 * 37;         // 32*33
        float* wks = wqs + 32 * 33;
        float* wvs = wks + 32 * 33;        // total 22.5 KB < 61.4 KB

        const int bg = blockIdx.x >> 4;
        const int part = blockIdx.x & 15;
        const int g = bg & 7;
        const int l0 = part * 36;

        const float* xp = x + (size_t)bg * 32 * LSP + l0;
        if (t < 288) {                      // 9 float4 per channel row
            const int d = t / 9, seg = t - d * 9;
            *(float4*)(xs + d * 40 + seg * 4) = *(const float4*)(xp + d * LSP + seg * 4);
        }
        {
            const int o = t >> 5, d = t & 31;   // exactly 1024 weights each
            wqs[o * 33 + d] = wq[(g * 32 + o) * 32 + d];
            wks[o * 33 + d] = wk[(g * 32 + o) * 32 + d];
            wvs[o * 33 + d] = wv[(g * 32 + o) * 32 + d];
        }
        __syncthreads();

        const float scale = 0.17677669529663687f * 1.4426950408889634f; // /sqrt(32)*log2e
        for (int idx = t; idx < 32 * 36; idx += 1024) {
            const int o = idx & 31;
            const int lloc = idx >> 5;
            const int l = l0 + lloc;
            float aq = 0.f, ak = 0.f, av = 0.f;
            #pragma unroll
            for (int d = 0; d < 32; d++) {
                const float xv = xs[d * 40 + lloc];
                aq = fmaf(wqs[o * 33 + d], xv, aq);
                ak = fmaf(wks[o * 33 + d], xv, ak);
                av = fmaf(wvs[o * 33 + d], xv, av);
            }
            aq *= scale;
            const int c = g * 32 + o;
            const float i2 = (float)(c & ~1);
            const float inv = __expf(-0.035977892078031968f * i2);   // ln(1e4)/256
            float sv, cv;
            __sincosf(inv * (float)l, &sv, &cv);
            ak += (c & 1) ? cv : sv;

            const size_t row = (size_t)bg * LSP + l;
            Qhi[row * 32 + o] = f2bf(aq);
            Khi[row * 32 + o] = f2bf(ak);
            vt[o * 37 + lloc] = av;
        }
        __syncthreads();

        for (int idx = t; idx < 32 * 36; idx += 1024) {  // permuted V tile write
            const int d = idx / 36;
            const int cc = idx - d * 36;
            const int n = bg * LSP + l0 + cc;
            const int k = n & 31;
            const int cperm = (k < 16) ? ((k >> 2) * 8 + (k & 3))
                                       : (((k - 16) >> 2) * 8 + ((k - 16) & 3) + 4);
            Vt[(size_t)(n >> 5) * 1024 + d * 32 + cperm] = f2bf(vt[d * 37 + cc]);
        }
    }

    __threadfence();                 // device-scope release of proj stores
    cg::this_grid().sync();          // all Q/K/V ready everywhere

    // ================= phase 2: attention (r12 loop + ones-MFMA lsum) =======
    const int wave = t >> 6, lane = t & 63;
    const int quad = lane >> 4, l16 = lane & 15;
    const int n0 = blockIdx.x * QB;

    unsigned short* psw = shm + wave * 48 * PSTR;   // wave-private P (32 cols)

    const bh8 qh0 = *(const bh8*)(Qhi + (size_t)(n0 + l16) * DH + quad * 8);
    const bh8 qh1 = *(const bh8*)(Qhi + (size_t)(n0 + 16 + l16) * DH + quad * 8);
    const bh8 qh2 = *(const bh8*)(Qhi + (size_t)(n0 + 32 + l16) * DH + quad * 8);

    const short oneb = (short)0x3F80;               // bf16 1.0
    const bh8 ones = {oneb, oneb, oneb, oneb, oneb, oneb, oneb, oneb};

    f4 o00 = {0.f,0.f,0.f,0.f}, o01 = {0.f,0.f,0.f,0.f};
    f4 o10 = {0.f,0.f,0.f,0.f}, o11 = {0.f,0.f,0.f,0.f};
    f4 o20 = {0.f,0.f,0.f,0.f}, o21 = {0.f,0.f,0.f,0.f};
    f4 lo0 = {0.f,0.f,0.f,0.f}, lo1 = {0.f,0.f,0.f,0.f}, lo2 = {0.f,0.f,0.f,0.f};
    const f4 zf = {0.f,0.f,0.f,0.f};

    const int kbase = wave * KPW;
    const int tile0 = kbase >> 5;           // 32-key subtile index base

    bh8 kfa0 = *(const bh8*)(Khi + (size_t)(kbase + l16) * DH + quad * 8);
    bh8 kfa1 = *(const bh8*)(Khi + (size_t)(kbase + 16 + l16) * DH + quad * 8);
    bh8 kfb0 = *(const bh8*)(Khi + (size_t)(kbase + 32 + l16) * DH + quad * 8);
    bh8 kfb1 = *(const bh8*)(Khi + (size_t)(kbase + 48 + l16) * DH + quad * 8);
    bh8 vfa0 = *(const bh8*)(Vt + (size_t)tile0 * 1024 + l16 * 32 + quad * 8);
    bh8 vfa1 = *(const bh8*)(Vt + (size_t)tile0 * 1024 + (16 + l16) * 32 + quad * 8);
    bh8 vfb0 = *(const bh8*)(Vt + (size_t)(tile0 + 1) * 1024 + l16 * 32 + quad * 8);
    bh8 vfb1 = *(const bh8*)(Vt + (size_t)(tile0 + 1) * 1024 + (16 + l16) * 32 + quad * 8);

    for (int it = 0; it < NTILE; ++it) {
        const int tn = (it + 1 < NTILE) ? it + 1 : it;
        const int kna = kbase + tn * 64;

        // ---- QK subtile a ----
        f4 s00 = MFMA(kfa0, qh0, zf);
        f4 s01 = MFMA(kfa0, qh1, zf);
        f4 s02 = MFMA(kfa0, qh2, zf);
        f4 s10 = MFMA(kfa1, qh0, zf);
        f4 s11 = MFMA(kfa1, qh1, zf);
        f4 s12 = MFMA(kfa1, qh2, zf);
        kfa0 = *(const bh8*)(Khi + (size_t)(kna + l16) * DH + quad * 8);
        kfa1 = *(const bh8*)(Khi + (size_t)(kna + 16 + l16) * DH + quad * 8);

        // ---- exp A + write P_A ----
        uint4 w0, w1, w2;
        {
            float a = fexp2(s00[0]), b = fexp2(s00[1]),
                  c = fexp2(s00[2]), d = fexp2(s00[3]);
            w0.x = pkbf(a, b); w0.y = pkbf(c, d);
            a = fexp2(s10[0]); b = fexp2(s10[1]);
            c = fexp2(s10[2]); d = fexp2(s10[3]);
            w0.z = pkbf(a, b); w0.w = pkbf(c, d);
            a = fexp2(s01[0]); b = fexp2(s01[1]);
            c = fexp2(s01[2]); d = fexp2(s01[3]);
            w1.x = pkbf(a, b); w1.y = pkbf(c, d);
            a = fexp2(s11[0]); b = fexp2(s11[1]);
            c = fexp2(s11[2]); d = fexp2(s11[3]);
            w1.z = pkbf(a, b); w1.w = pkbf(c, d);
            a = fexp2(s02[0]); b = fexp2(s02[1]);
            c = fexp2(s02[2]); d = fexp2(s02[3]);
            w2.x = pkbf(a, b); w2.y = pkbf(c, d);
            a = fexp2(s12[0]); b = fexp2(s12[1]);
            c = fexp2(s12[2]); d = fexp2(s12[3]);
            w2.z = pkbf(a, b); w2.w = pkbf(c, d);
        }
        *(uint4*)(psw + l16 * PSTR + quad * 8) = w0;
        *(uint4*)(psw + (16 + l16) * PSTR + quad * 8) = w1;
        *(uint4*)(psw + (32 + l16) * PSTR + quad * 8) = w2;

        // ---- QK subtile b (hides writeA->readA latency) ----
        f4 b00 = MFMA(kfb0, qh0, zf);
        f4 b01 = MFMA(kfb0, qh1, zf);
        f4 b02 = MFMA(kfb0, qh2, zf);
        f4 b10 = MFMA(kfb1, qh0, zf);
        f4 b11 = MFMA(kfb1, qh1, zf);
        f4 b12 = MFMA(kfb1, qh2, zf);
        kfb0 = *(const bh8*)(Khi + (size_t)(kna + 32 + l16) * DH + quad * 8);
        kfb1 = *(const bh8*)(Khi + (size_t)(kna + 48 + l16) * DH + quad * 8);

        // ---- exp B (P_B in regs until P_A consumed) ----
        uint4 u0, u1, u2;
        {
            float a = fexp2(b00[0]), b = fexp2(b00[1]),
                  c = fexp2(b00[2]), d = fexp2(b00[3]);
            u0.x = pkbf(a, b); u0.y = pkbf(c, d);
            a = fexp2(b10[0]); b = fexp2(b10[1]);
            c = fexp2(b10[2]); d = fexp2(b10[3]);
            u0.z = pkbf(a, b); u0.w = pkbf(c, d);
            a = fexp2(b01[0]); b = fexp2(b01[1]);
            c = fexp2(b01[2]); d = fexp2(b01[3]);
            u1.x = pkbf(a, b); u1.y = pkbf(c, d);
            a = fexp2(b11[0]); b = fexp2(b11[1]);
            c = fexp2(b11[2]); d = fexp2(b11[3]);
            u1.z = pkbf(a, b); u1.w = pkbf(c, d);
            a = fexp2(b02[0]); b = fexp2(b02[1]);
            c = fexp2(b02[2]); d = fexp2(b02[3]);
            u2.x = pkbf(a, b); u2.y = pkbf(c, d);
            a = fexp2(b12[0]); b = fexp2(b12[1]);
            c = fexp2(b12[2]); d = fexp2(b12[3]);
            u2.z = pkbf(a, b); u2.w = pkbf(c, d);
        }

        // ---- read P_A + PV-a + lsum-a on MFMA pipe ----
        {
            const bh8 pa0 = *(const bh8*)(psw + l16 * PSTR + quad * 8);
            const bh8 pa1 = *(const bh8*)(psw + (16 + l16) * PSTR + quad * 8);
            const bh8 pa2 = *(const bh8*)(psw + (32 + l16) * PSTR + quad * 8);
            o00 = MFMA(pa0, vfa0, o00); o01 = MFMA(pa0, vfa1, o01);
            o10 = MFMA(pa1, vfa0, o10); o11 = MFMA(pa1, vfa1, o11);
            o20 = MFMA(pa2, vfa0, o20); o21 = MFMA(pa2, vfa1, o21);
            lo0 = MFMA(pa0, ones, lo0);
            lo1 = MFMA(pa1, ones, lo1);
            lo2 = MFMA(pa2, ones, lo2);
        }
        vfa0 = *(const bh8*)(Vt + (size_t)(tile0 + 2 * tn) * 1024 + l16 * 32 + quad * 8);
        vfa1 = *(const bh8*)(Vt + (size_t)(tile0 + 2 * tn) * 1024 + (16 + l16) * 32 + quad * 8);

        // ---- write P_B (after readA issued: per-wave DS in-order) ----
        *(uint4*)(psw + l16 * PSTR + quad * 8) = u0;
        *(uint4*)(psw + (16 + l16) * PSTR + quad * 8) = u1;
        *(uint4*)(psw + (32 + l16) * PSTR + quad * 8) = u2;

        // ---- read P_B + PV-b + lsum-b ----
        {
            const bh8 pb0 = *(const bh8*)(psw + l16 * PSTR + quad * 8);
            const bh8 pb1 = *(const bh8*)(psw + (16 + l16) * PSTR + quad * 8);
            const bh8 pb2 = *(const bh8*)(psw + (32 + l16) * PSTR + quad * 8);
            o00 = MFMA(pb0, vfb0, o00); o01 = MFMA(pb0, vfb1, o01);
            o10 = MFMA(pb1, vfb0, o10); o11 = MFMA(pb1, vfb1, o11);
            o20 = MFMA(pb2, vfb0, o20); o21 = MFMA(pb2, vfb1, o21);
            lo0 = MFMA(pb0, ones, lo0);
            lo1 = MFMA(pb1, ones, lo1);
            lo2 = MFMA(pb2, ones, lo2);
        }
        vfb0 = *(const bh8*)(Vt + (size_t)(tile0 + 2 * tn + 1) * 1024 + l16 * 32 + quad * 8);
        vfb1 = *(const bh8*)(Vt + (size_t)(tile0 + 2 * tn + 1) * 1024 + (16 + l16) * 32 + quad * 8);
    }

    // two-stage additive merge: waves 0..7 write planes, waves 8..15 add in
    __syncthreads();
    float* mo = (float*)shm;                 // [8][32*48] = 49.2 KB
    float* mls = mo + 8 * 1536;              // [8][48]
    const int mw = wave & 7;
    float* mp = mo + mw * 1536;
    if (wave < 8) {
        #pragma unroll
        for (int reg = 0; reg < 4; ++reg) {
            const int q0 = quad * 4 + reg;
            mp[l16 * 48 + q0]             = o00[reg];
            mp[(16 + l16) * 48 + q0]      = o01[reg];
            mp[l16 * 48 + 16 + q0]        = o10[reg];
            mp[(16 + l16) * 48 + 16 + q0] = o11[reg];
            mp[l16 * 48 + 32 + q0]        = o20[reg];
            mp[(16 + l16) * 48 + 32 + q0] = o21[reg];
        }
        if (l16 == 0) {
            #pragma unroll
            for (int reg = 0; reg < 4; ++reg) {
                mls[mw * 48 + quad * 4 + reg]      = lo0[reg];   // cols replicated
                mls[mw * 48 + 16 + quad * 4 + reg] = lo1[reg];
                mls[mw * 48 + 32 + quad * 4 + reg] = lo2[reg];
            }
        }
    }
    __syncthreads();
    if (wave >= 8) {
        #pragma unroll
        for (int reg = 0; reg < 4; ++reg) {
            const int q0 = quad * 4 + reg;
            mp[l16 * 48 + q0]             += o00[reg];
            mp[(16 + l16) * 48 + q0]      += o01[reg];
            mp[l16 * 48 + 16 + q0]        += o10[reg];
            mp[(16 + l16) * 48 + 16 + q0] += o11[reg];
            mp[l16 * 48 + 32 + q0]        += o20[reg];
            mp[(16 + l16) * 48 + 32 + q0] += o21[reg];
        }
        if (l16 == 0) {
            #pragma unroll
            for (int reg = 0; reg < 4; ++reg) {
                mls[mw * 48 + quad * 4 + reg]      += lo0[reg];
                mls[mw * 48 + 16 + quad * 4 + reg] += lo1[reg];
                mls[mw * 48 + 32 + quad * 4 + reg] += lo2[reg];
            }
        }
    }
    __syncthreads();

    const int bg = n0 / LSP;
    const int l0 = n0 - bg * LSP;
    for (int c = t; c < 32 * QB; c += 1024) {
        const int d = c / QB;
        const int q = c - d * QB;
        float num = 0.f, den = 0.f;
        #pragma unroll
        for (int w2 = 0; w2 < 8; ++w2) {
            num += mo[w2 * 1536 + d * 48 + q];
            den += mls[w2 * 48 + q];
        }
        out[((size_t)(bg * 32 + d)) * LSP + l0 + q] = num / den;
    }
}

extern "C" void kernel_launch(void* const* d_in, const int* in_sizes, int n_in,
                              void* d_out, int out_size, void* d_ws, size_t ws_size,
                              hipStream_t stream) {
    (void)in_sizes; (void)n_in; (void)out_size; (void)ws_size;
    const float* x  = (const float*)d_in[0];
    const float* wq = (const float*)d_in[1];
    const float* wk = (const float*)d_in[2];
    const float* wv = (const float*)d_in[3];

    unsigned short* ws = (unsigned short*)d_ws;
    unsigned short* Qhi = ws;
    unsigned short* Khi = ws + SZP;
    unsigned short* Vt  = ws + 2 * SZP;
    float* out = (float*)d_out;

    void* args[] = {(void*)&x, (void*)&wq, (void*)&wk, (void*)&wv,
                    (void*)&Qhi, (void*)&Khi, (void*)&Vt, (void*)&out};
    hipLaunchCooperativeKernel((const void*)sa_fused_kernel, dim3(256), dim3(1024),
                               args, 0, stream);
}

// Round 15
// 95.718 us; speedup vs baseline: 2.0626x; 2.0626x over previous
//
#include <hip/hip_runtime.h>
#include <hip/hip_bf16.h>

// Round 15: revert r14's cooperative fusion (grid.sync cost ~80us). Base =
// r12 (best, 90.66us), single isolated change: lsum on the MFMA pipe via
// ones-fragment (removes ~48 VALU adds/iter + end shuffles from the busiest
// pipe; P frags already in regs for PV). r10 proved this numerically.

#define LSP   576
#define NROW  9216
#define DH    32
#define NW    16              // waves per attn block
#define KPW   (NROW / NW)     // 576 keys per wave
#define NTILE 9               // 9 x 64-key iterations (2 x 32-key subtiles)
#define PSTR  40              // P LDS row stride (ushort): 32 keys + 8 pad
#define QB    36              // queries per attn block (grid = 256 exactly)
#define SZ    ((size_t)NROW * DH)
#define SZP   (SZ + 4096)     // pad: ghost-row reads stay in-bounds

typedef __attribute__((ext_vector_type(8))) short bh8;
typedef __attribute__((ext_vector_type(4))) float f4;

static __device__ __forceinline__ unsigned short f2bf(float x) {
    union { float f; unsigned int i; } w; w.f = x;
    unsigned int u = w.i;
    return (unsigned short)((u + 0x7fffu + ((u >> 16) & 1u)) >> 16);
}
static __device__ __forceinline__ unsigned int pkbf(float a, float b) {
    union { __hip_bfloat162 h2; unsigned int u; } w;
    w.h2 = __float22bfloat162_rn(make_float2(a, b));   // a -> low ushort (RNE)
    return w.u;
}
static __device__ __forceinline__ float fexp2(float x) {
#if __has_builtin(__builtin_amdgcn_exp2f)
    return __builtin_amdgcn_exp2f(x);
#else
    return exp2f(x);
#endif
}

#define MFMA(a, b, c) __builtin_amdgcn_mfma_f32_16x16x32_bf16(a, b, c, 0, 0, 0)

// ---------------- projections + PE -> Qhi/Khi [n][32], V permuted tiles -----
// Q pre-scaled by 1/sqrt(d)*log2(e) (exp2-folded softmax).
// Vt tile layout [n>>5][d][cperm]; cperm makes P A-rows and V B-frags contiguous.
__global__ __launch_bounds__(256) void sa_proj_kernel(
    const float* __restrict__ x,
    const float* __restrict__ wq, const float* __restrict__ wk, const float* __restrict__ wv,
    unsigned short* __restrict__ Qhi, unsigned short* __restrict__ Khi,
    unsigned short* __restrict__ Vt)
{
    __shared__ __align__(16) float xs[32 * 40];
    __shared__ float vt[32 * 37];
    __shared__ float wqs[32 * 33], wks[32 * 33], wvs[32 * 33];
    const int t = threadIdx.x;
    const int bg = blockIdx.x >> 4;
    const int part = blockIdx.x & 15;
    const int g = bg & 7;
    const int l0 = part * 36;

    const float* xp = x + (size_t)bg * 32 * LSP + l0;
    for (int i = t; i < 32 * 9; i += 256) {
        int d = i / 9, seg = i % 9;
        *(float4*)(xs + d * 40 + seg * 4) = *(const float4*)(xp + d * LSP + seg * 4);
    }
    for (int i = t; i < 1024; i += 256) {
        int o = i >> 5, d = i & 31;
        wqs[o * 33 + d] = wq[(g * 32 + o) * 32 + d];
        wks[o * 33 + d] = wk[(g * 32 + o) * 32 + d];
        wvs[o * 33 + d] = wv[(g * 32 + o) * 32 + d];
    }
    __syncthreads();

    // 1/sqrt(32) * log2(e): fold exp->exp2
    const float scale = 0.17677669529663687f * 1.4426950408889634f;
    for (int idx = t; idx < 32 * 36; idx += 256) {
        const int o = idx & 31;
        const int lloc = idx >> 5;
        const int l = l0 + lloc;
        float aq = 0.f, ak = 0.f, av = 0.f;
        #pragma unroll
        for (int d = 0; d < 32; d++) {
            const float xv = xs[d * 40 + lloc];
            aq = fmaf(wqs[o * 33 + d], xv, aq);
            ak = fmaf(wks[o * 33 + d], xv, ak);
            av = fmaf(wvs[o * 33 + d], xv, av);
        }
        aq *= scale;
        const int c = g * 32 + o;
        const float i2 = (float)(c & ~1);
        const float inv = __expf(-0.035977892078031968f * i2);   // ln(1e4)/256
        float sv, cv;
        __sincosf(inv * (float)l, &sv, &cv);
        ak += (c & 1) ? cv : sv;

        const size_t row = (size_t)bg * LSP + l;
        Qhi[row * 32 + o] = f2bf(aq);
        Khi[row * 32 + o] = f2bf(ak);
        vt[o * 37 + lloc] = av;
    }
    __syncthreads();

    for (int idx = t; idx < 32 * 36; idx += 256) {     // permuted V tile write
        const int d = idx / 36;
        const int cc = idx - d * 36;
        const int n = bg * LSP + l0 + cc;
        const int k = n & 31;
        const int cperm = (k < 16) ? ((k >> 2) * 8 + (k & 3))
                                   : (((k - 16) >> 2) * 8 + ((k - 16) & 3) + 4);
        Vt[(size_t)(n >> 5) * 1024 + d * 32 + cperm] = f2bf(vt[d * 37 + cc]);
    }
}

// ---------------- fused attention: in-block split (16 waves) + LDS merge ----
// grid 256 x 1024 threads = 16 waves; block owns QB=36 queries (rows 36..47
// ghosts); wave w owns keys [w*576,(w+1)*576). 64 keys/iter as 2 subtiles with
// interleaved LDS round-trips. Main loop barrier-free (wave-private P).
__global__ __launch_bounds__(1024, 4) void sa_attn_kernel(
    const unsigned short* __restrict__ Qhi, const unsigned short* __restrict__ Khi,
    const unsigned short* __restrict__ Vt, float* __restrict__ out)
{
    __shared__ __align__(16) unsigned short shm[NW * 48 * PSTR];  // 61.4 KB
    const int t = threadIdx.x;
    const int wave = t >> 6, lane = t & 63;
    const int quad = lane >> 4, l16 = lane & 15;
    const int n0 = blockIdx.x * QB;

    unsigned short* psw = shm + wave * 48 * PSTR;   // wave-private P (32 cols)

    // Q B-fragments (3 row-groups of 16; rows 36..47 are ghosts -> tiny poison)
    const bh8 qh0 = *(const bh8*)(Qhi + (size_t)(n0 + l16) * DH + quad * 8);
    const bh8 qh1 = *(const bh8*)(Qhi + (size_t)(n0 + 16 + l16) * DH + quad * 8);
    const bh8 qh2 = *(const bh8*)(Qhi + (size_t)(n0 + 32 + l16) * DH + quad * 8);

    const short oneb = (short)0x3F80;               // bf16 1.0
    const bh8 ones = {oneb, oneb, oneb, oneb, oneb, oneb, oneb, oneb};

    f4 o00 = {0.f,0.f,0.f,0.f}, o01 = {0.f,0.f,0.f,0.f};
    f4 o10 = {0.f,0.f,0.f,0.f}, o11 = {0.f,0.f,0.f,0.f};
    f4 o20 = {0.f,0.f,0.f,0.f}, o21 = {0.f,0.f,0.f,0.f};
    f4 lo0 = {0.f,0.f,0.f,0.f}, lo1 = {0.f,0.f,0.f,0.f}, lo2 = {0.f,0.f,0.f,0.f};
    const f4 zf = {0.f,0.f,0.f,0.f};

    const int kbase = wave * KPW;
    const int tile0 = kbase >> 5;           // 32-key subtile index base

    // prefetch iteration 0: subtiles a (keys 0..31), b (keys 32..63)
    bh8 kfa0 = *(const bh8*)(Khi + (size_t)(kbase + l16) * DH + quad * 8);
    bh8 kfa1 = *(const bh8*)(Khi + (size_t)(kbase + 16 + l16) * DH + quad * 8);
    bh8 kfb0 = *(const bh8*)(Khi + (size_t)(kbase + 32 + l16) * DH + quad * 8);
    bh8 kfb1 = *(const bh8*)(Khi + (size_t)(kbase + 48 + l16) * DH + quad * 8);
    bh8 vfa0 = *(const bh8*)(Vt + (size_t)tile0 * 1024 + l16 * 32 + quad * 8);
    bh8 vfa1 = *(const bh8*)(Vt + (size_t)tile0 * 1024 + (16 + l16) * 32 + quad * 8);
    bh8 vfb0 = *(const bh8*)(Vt + (size_t)(tile0 + 1) * 1024 + l16 * 32 + quad * 8);
    bh8 vfb1 = *(const bh8*)(Vt + (size_t)(tile0 + 1) * 1024 + (16 + l16) * 32 + quad * 8);

    for (int it = 0; it < NTILE; ++it) {
        const int tn = (it + 1 < NTILE) ? it + 1 : it;
        const int kna = kbase + tn * 64;

        // ---- QK subtile a ----
        f4 s00 = MFMA(kfa0, qh0, zf);
        f4 s01 = MFMA(kfa0, qh1, zf);
        f4 s02 = MFMA(kfa0, qh2, zf);
        f4 s10 = MFMA(kfa1, qh0, zf);
        f4 s11 = MFMA(kfa1, qh1, zf);
        f4 s12 = MFMA(kfa1, qh2, zf);
        kfa0 = *(const bh8*)(Khi + (size_t)(kna + l16) * DH + quad * 8);
        kfa1 = *(const bh8*)(Khi + (size_t)(kna + 16 + l16) * DH + quad * 8);

        // ---- exp A + write P_A ----
        uint4 w0, w1, w2;
        {
            float a = fexp2(s00[0]), b = fexp2(s00[1]),
                  c = fexp2(s00[2]), d = fexp2(s00[3]);
            w0.x = pkbf(a, b); w0.y = pkbf(c, d);
            a = fexp2(s10[0]); b = fexp2(s10[1]);
            c = fexp2(s10[2]); d = fexp2(s10[3]);
            w0.z = pkbf(a, b); w0.w = pkbf(c, d);
            a = fexp2(s01[0]); b = fexp2(s01[1]);
            c = fexp2(s01[2]); d = fexp2(s01[3]);
            w1.x = pkbf(a, b); w1.y = pkbf(c, d);
            a = fexp2(s11[0]); b = fexp2(s11[1]);
            c = fexp2(s11[2]); d = fexp2(s11[3]);
            w1.z = pkbf(a, b); w1.w = pkbf(c, d);
            a = fexp2(s02[0]); b = fexp2(s02[1]);
            c = fexp2(s02[2]); d = fexp2(s02[3]);
            w2.x = pkbf(a, b); w2.y = pkbf(c, d);
            a = fexp2(s12[0]); b = fexp2(s12[1]);
            c = fexp2(s12[2]); d = fexp2(s12[3]);
            w2.z = pkbf(a, b); w2.w = pkbf(c, d);
        }
        *(uint4*)(psw + l16 * PSTR + quad * 8) = w0;
        *(uint4*)(psw + (16 + l16) * PSTR + quad * 8) = w1;
        *(uint4*)(psw + (32 + l16) * PSTR + quad * 8) = w2;

        // ---- QK subtile b (hides writeA->readA latency) ----
        f4 b00 = MFMA(kfb0, qh0, zf);
        f4 b01 = MFMA(kfb0, qh1, zf);
        f4 b02 = MFMA(kfb0, qh2, zf);
        f4 b10 = MFMA(kfb1, qh0, zf);
        f4 b11 = MFMA(kfb1, qh1, zf);
        f4 b12 = MFMA(kfb1, qh2, zf);
        kfb0 = *(const bh8*)(Khi + (size_t)(kna + 32 + l16) * DH + quad * 8);
        kfb1 = *(const bh8*)(Khi + (size_t)(kna + 48 + l16) * DH + quad * 8);

        // ---- exp B (P_B stays in regs until P_A consumed) ----
        uint4 u0, u1, u2;
        {
            float a = fexp2(b00[0]), b = fexp2(b00[1]),
                  c = fexp2(b00[2]), d = fexp2(b00[3]);
            u0.x = pkbf(a, b); u0.y = pkbf(c, d);
            a = fexp2(b10[0]); b = fexp2(b10[1]);
            c = fexp2(b10[2]); d = fexp2(b10[3]);
            u0.z = pkbf(a, b); u0.w = pkbf(c, d);
            a = fexp2(b01[0]); b = fexp2(b01[1]);
            c = fexp2(b01[2]); d = fexp2(b01[3]);
            u1.x = pkbf(a, b); u1.y = pkbf(c, d);
            a = fexp2(b11[0]); b = fexp2(b11[1]);
            c = fexp2(b11[2]); d = fexp2(b11[3]);
            u1.z = pkbf(a, b); u1.w = pkbf(c, d);
            a = fexp2(b02[0]); b = fexp2(b02[1]);
            c = fexp2(b02[2]); d = fexp2(b02[3]);
            u2.x = pkbf(a, b); u2.y = pkbf(c, d);
            a = fexp2(b12[0]); b = fexp2(b12[1]);
            c = fexp2(b12[2]); d = fexp2(b12[3]);
            u2.z = pkbf(a, b); u2.w = pkbf(c, d);
        }

        // ---- read P_A + PV-a + lsum-a on the MFMA pipe ----
        {
            const bh8 pa0 = *(const bh8*)(psw + l16 * PSTR + quad * 8);
            const bh8 pa1 = *(const bh8*)(psw + (16 + l16) * PSTR + quad * 8);
            const bh8 pa2 = *(const bh8*)(psw + (32 + l16) * PSTR + quad * 8);
            o00 = MFMA(pa0, vfa0, o00); o01 = MFMA(pa0, vfa1, o01);
            o10 = MFMA(pa1, vfa0, o10); o11 = MFMA(pa1, vfa1, o11);
            o20 = MFMA(pa2, vfa0, o20); o21 = MFMA(pa2, vfa1, o21);
            lo0 = MFMA(pa0, ones, lo0);
            lo1 = MFMA(pa1, ones, lo1);
            lo2 = MFMA(pa2, ones, lo2);
        }
        vfa0 = *(const bh8*)(Vt + (size_t)(tile0 + 2 * tn) * 1024 + l16 * 32 + quad * 8);
        vfa1 = *(const bh8*)(Vt + (size_t)(tile0 + 2 * tn) * 1024 + (16 + l16) * 32 + quad * 8);

        // ---- write P_B (after readA issued: per-wave DS in-order => safe) ----
        *(uint4*)(psw + l16 * PSTR + quad * 8) = u0;
        *(uint4*)(psw + (16 + l16) * PSTR + quad * 8) = u1;
        *(uint4*)(psw + (32 + l16) * PSTR + quad * 8) = u2;

        // ---- read P_B + PV-b + lsum-b ----
        {
            const bh8 pb0 = *(const bh8*)(psw + l16 * PSTR + quad * 8);
            const bh8 pb1 = *(const bh8*)(psw + (16 + l16) * PSTR + quad * 8);
            const bh8 pb2 = *(const bh8*)(psw + (32 + l16) * PSTR + quad * 8);
            o00 = MFMA(pb0, vfb0, o00); o01 = MFMA(pb0, vfb1, o01);
            o10 = MFMA(pb1, vfb0, o10); o11 = MFMA(pb1, vfb1, o11);
            o20 = MFMA(pb2, vfb0, o20); o21 = MFMA(pb2, vfb1, o21);
            lo0 = MFMA(pb0, ones, lo0);
            lo1 = MFMA(pb1, ones, lo1);
            lo2 = MFMA(pb2, ones, lo2);
        }
        vfb0 = *(const bh8*)(Vt + (size_t)(tile0 + 2 * tn + 1) * 1024 + l16 * 32 + quad * 8);
        vfb1 = *(const bh8*)(Vt + (size_t)(tile0 + 2 * tn + 1) * 1024 + (16 + l16) * 32 + quad * 8);
    }

    // two-stage additive merge: waves 0..7 write planes, waves 8..15 add in
    __syncthreads();
    float* mo = (float*)shm;                 // [8][32*48] = 49.2 KB
    float* mls = mo + 8 * 1536;              // [8][48]
    const int mw = wave & 7;
    float* mp = mo + mw * 1536;
    if (wave < 8) {
        #pragma unroll
        for (int reg = 0; reg < 4; ++reg) {
            const int q0 = quad * 4 + reg;
            mp[l16 * 48 + q0]             = o00[reg];
            mp[(16 + l16) * 48 + q0]      = o01[reg];
            mp[l16 * 48 + 16 + q0]        = o10[reg];
            mp[(16 + l16) * 48 + 16 + q0] = o11[reg];
            mp[l16 * 48 + 32 + q0]        = o20[reg];
            mp[(16 + l16) * 48 + 32 + q0] = o21[reg];
        }
        if (l16 == 0) {                      // lsum C-layout: row=q, all cols equal
            #pragma unroll
            for (int reg = 0; reg < 4; ++reg) {
                mls[mw * 48 + quad * 4 + reg]      = lo0[reg];
                mls[mw * 48 + 16 + quad * 4 + reg] = lo1[reg];
                mls[mw * 48 + 32 + quad * 4 + reg] = lo2[reg];
            }
        }
    }
    __syncthreads();
    if (wave >= 8) {
        #pragma unroll
        for (int reg = 0; reg < 4; ++reg) {
            const int q0 = quad * 4 + reg;
            mp[l16 * 48 + q0]             += o00[reg];
            mp[(16 + l16) * 48 + q0]      += o01[reg];
            mp[l16 * 48 + 16 + q0]        += o10[reg];
            mp[(16 + l16) * 48 + 16 + q0] += o11[reg];
            mp[l16 * 48 + 32 + q0]        += o20[reg];
            mp[(16 + l16) * 48 + 32 + q0] += o21[reg];
        }
        if (l16 == 0) {
            #pragma unroll
            for (int reg = 0; reg < 4; ++reg) {
                mls[mw * 48 + quad * 4 + reg]      += lo0[reg];
                mls[mw * 48 + 16 + quad * 4 + reg] += lo1[reg];
                mls[mw * 48 + 32 + quad * 4 + reg] += lo2[reg];
            }
        }
    }
    __syncthreads();

    const int bg = n0 / LSP;
    const int l0 = n0 - bg * LSP;
    for (int c = t; c < 32 * QB; c += 1024) {
        const int d = c / QB;
        const int q = c - d * QB;
        float num = 0.f, den = 0.f;
        #pragma unroll
        for (int w2 = 0; w2 < 8; ++w2) {
            num += mo[w2 * 1536 + d * 48 + q];
            den += mls[w2 * 48 + q];
        }
        out[((size_t)(bg * 32 + d)) * LSP + l0 + q] = num / den;
    }
}

extern "C" void kernel_launch(void* const* d_in, const int* in_sizes, int n_in,
                              void* d_out, int out_size, void* d_ws, size_t ws_size,
                              hipStream_t stream) {
    (void)in_sizes; (void)n_in; (void)out_size; (void)ws_size;
    const float* x  = (const float*)d_in[0];
    const float* wq = (const float*)d_in[1];
    const float* wk = (const float*)d_in[2];
    const float* wv = (const float*)d_in[3];

    unsigned short* ws = (unsigned short*)d_ws;
    unsigned short* Qhi = ws;
    unsigned short* Khi = ws + SZP;
    unsigned short* Vt  = ws + 2 * SZP;
    float* out = (float*)d_out;

    sa_proj_kernel<<<256, 256, 0, stream>>>(x, wq, wk, wv, Qhi, Khi, Vt);
    sa_attn_kernel<<<256, 1024, 0, stream>>>(Qhi, Khi, Vt, out);
}

// Round 16
// 90.509 us; speedup vs baseline: 2.1813x; 1.0576x over previous
//
#include <hip/hip_runtime.h>
#include <hip/hip_bf16.h>

// Round 16: base = r12 (verified best, 90.66us; r13/r14/r15 all regressed and
// were reverted). Single change: V prefetch hoisted to the top of the
// iteration (temps + rotate) -> ~800 cyc lead instead of ~200, covering L2
// latency. Everything else byte-identical to r12.

#define LSP   576
#define NROW  9216
#define DH    32
#define NW    16              // waves per attn block
#define KPW   (NROW / NW)     // 576 keys per wave
#define NTILE 9               // 9 x 64-key iterations (2 x 32-key subtiles)
#define PSTR  40              // P LDS row stride (ushort): 32 keys + 8 pad
#define QB    36              // queries per attn block (grid = 256 exactly)
#define SZ    ((size_t)NROW * DH)
#define SZP   (SZ + 4096)     // pad: ghost-row reads stay in-bounds

typedef __attribute__((ext_vector_type(8))) short bh8;
typedef __attribute__((ext_vector_type(4))) float f4;

static __device__ __forceinline__ unsigned short f2bf(float x) {
    union { float f; unsigned int i; } w; w.f = x;
    unsigned int u = w.i;
    return (unsigned short)((u + 0x7fffu + ((u >> 16) & 1u)) >> 16);
}
static __device__ __forceinline__ unsigned int pkbf(float a, float b) {
    union { __hip_bfloat162 h2; unsigned int u; } w;
    w.h2 = __float22bfloat162_rn(make_float2(a, b));   // a -> low ushort (RNE)
    return w.u;
}
static __device__ __forceinline__ float fexp2(float x) {
#if __has_builtin(__builtin_amdgcn_exp2f)
    return __builtin_amdgcn_exp2f(x);
#else
    return exp2f(x);
#endif
}

#define MFMA(a, b, c) __builtin_amdgcn_mfma_f32_16x16x32_bf16(a, b, c, 0, 0, 0)

// ---------------- projections + PE -> Qhi/Khi [n][32], V permuted tiles -----
// Q pre-scaled by 1/sqrt(d)*log2(e) (exp2-folded softmax).
// Vt tile layout [n>>5][d][cperm]; cperm makes P A-rows and V B-frags contiguous.
__global__ __launch_bounds__(256) void sa_proj_kernel(
    const float* __restrict__ x,
    const float* __restrict__ wq, const float* __restrict__ wk, const float* __restrict__ wv,
    unsigned short* __restrict__ Qhi, unsigned short* __restrict__ Khi,
    unsigned short* __restrict__ Vt)
{
    __shared__ __align__(16) float xs[32 * 40];
    __shared__ float vt[32 * 37];
    __shared__ float wqs[32 * 33], wks[32 * 33], wvs[32 * 33];
    const int t = threadIdx.x;
    const int bg = blockIdx.x >> 4;
    const int part = blockIdx.x & 15;
    const int g = bg & 7;
    const int l0 = part * 36;

    const float* xp = x + (size_t)bg * 32 * LSP + l0;
    for (int i = t; i < 32 * 9; i += 256) {
        int d = i / 9, seg = i % 9;
        *(float4*)(xs + d * 40 + seg * 4) = *(const float4*)(xp + d * LSP + seg * 4);
    }
    for (int i = t; i < 1024; i += 256) {
        int o = i >> 5, d = i & 31;
        wqs[o * 33 + d] = wq[(g * 32 + o) * 32 + d];
        wks[o * 33 + d] = wk[(g * 32 + o) * 32 + d];
        wvs[o * 33 + d] = wv[(g * 32 + o) * 32 + d];
    }
    __syncthreads();

    // 1/sqrt(32) * log2(e): fold exp->exp2
    const float scale = 0.17677669529663687f * 1.4426950408889634f;
    for (int idx = t; idx < 32 * 36; idx += 256) {
        const int o = idx & 31;
        const int lloc = idx >> 5;
        const int l = l0 + lloc;
        float aq = 0.f, ak = 0.f, av = 0.f;
        #pragma unroll
        for (int d = 0; d < 32; d++) {
            const float xv = xs[d * 40 + lloc];
            aq = fmaf(wqs[o * 33 + d], xv, aq);
            ak = fmaf(wks[o * 33 + d], xv, ak);
            av = fmaf(wvs[o * 33 + d], xv, av);
        }
        aq *= scale;
        const int c = g * 32 + o;
        const float i2 = (float)(c & ~1);
        const float inv = __expf(-0.035977892078031968f * i2);   // ln(1e4)/256
        float sv, cv;
        __sincosf(inv * (float)l, &sv, &cv);
        ak += (c & 1) ? cv : sv;

        const size_t row = (size_t)bg * LSP + l;
        Qhi[row * 32 + o] = f2bf(aq);
        Khi[row * 32 + o] = f2bf(ak);
        vt[o * 37 + lloc] = av;
    }
    __syncthreads();

    for (int idx = t; idx < 32 * 36; idx += 256) {     // permuted V tile write
        const int d = idx / 36;
        const int cc = idx - d * 36;
        const int n = bg * LSP + l0 + cc;
        const int k = n & 31;
        const int cperm = (k < 16) ? ((k >> 2) * 8 + (k & 3))
                                   : (((k - 16) >> 2) * 8 + ((k - 16) & 3) + 4);
        Vt[(size_t)(n >> 5) * 1024 + d * 32 + cperm] = f2bf(vt[d * 37 + cc]);
    }
}

// ---------------- fused attention: in-block split (16 waves) + LDS merge ----
// grid 256 x 1024 threads = 16 waves; block owns QB=36 queries (rows 36..47
// ghosts); wave w owns keys [w*576,(w+1)*576). 64 keys/iter as 2 subtiles with
// interleaved LDS round-trips. Main loop barrier-free (wave-private P).
__global__ __launch_bounds__(1024, 4) void sa_attn_kernel(
    const unsigned short* __restrict__ Qhi, const unsigned short* __restrict__ Khi,
    const unsigned short* __restrict__ Vt, float* __restrict__ out)
{
    __shared__ __align__(16) unsigned short shm[NW * 48 * PSTR];  // 61.4 KB
    const int t = threadIdx.x;
    const int wave = t >> 6, lane = t & 63;
    const int quad = lane >> 4, l16 = lane & 15;
    const int n0 = blockIdx.x * QB;

    unsigned short* psw = shm + wave * 48 * PSTR;   // wave-private P (32 cols)

    // Q B-fragments (3 row-groups of 16; rows 36..47 are ghosts -> tiny poison)
    const bh8 qh0 = *(const bh8*)(Qhi + (size_t)(n0 + l16) * DH + quad * 8);
    const bh8 qh1 = *(const bh8*)(Qhi + (size_t)(n0 + 16 + l16) * DH + quad * 8);
    const bh8 qh2 = *(const bh8*)(Qhi + (size_t)(n0 + 32 + l16) * DH + quad * 8);

    f4 o00 = {0.f,0.f,0.f,0.f}, o01 = {0.f,0.f,0.f,0.f};
    f4 o10 = {0.f,0.f,0.f,0.f}, o11 = {0.f,0.f,0.f,0.f};
    f4 o20 = {0.f,0.f,0.f,0.f}, o21 = {0.f,0.f,0.f,0.f};
    float ls0 = 0.f, ls1 = 0.f, ls2 = 0.f;
    const f4 zf = {0.f,0.f,0.f,0.f};

    const int kbase = wave * KPW;
    const int tile0 = kbase >> 5;           // 32-key subtile index base

    // prefetch iteration 0: subtiles a (keys 0..31), b (keys 32..63)
    bh8 kfa0 = *(const bh8*)(Khi + (size_t)(kbase + l16) * DH + quad * 8);
    bh8 kfa1 = *(const bh8*)(Khi + (size_t)(kbase + 16 + l16) * DH + quad * 8);
    bh8 kfb0 = *(const bh8*)(Khi + (size_t)(kbase + 32 + l16) * DH + quad * 8);
    bh8 kfb1 = *(const bh8*)(Khi + (size_t)(kbase + 48 + l16) * DH + quad * 8);
    bh8 vfa0 = *(const bh8*)(Vt + (size_t)tile0 * 1024 + l16 * 32 + quad * 8);
    bh8 vfa1 = *(const bh8*)(Vt + (size_t)tile0 * 1024 + (16 + l16) * 32 + quad * 8);
    bh8 vfb0 = *(const bh8*)(Vt + (size_t)(tile0 + 1) * 1024 + l16 * 32 + quad * 8);
    bh8 vfb1 = *(const bh8*)(Vt + (size_t)(tile0 + 1) * 1024 + (16 + l16) * 32 + quad * 8);

    for (int it = 0; it < NTILE; ++it) {
        const int tn = (it + 1 < NTILE) ? it + 1 : it;
        const int kna = kbase + tn * 64;

        // ---- QK subtile a ----
        f4 s00 = MFMA(kfa0, qh0, zf);
        f4 s01 = MFMA(kfa0, qh1, zf);
        f4 s02 = MFMA(kfa0, qh2, zf);
        f4 s10 = MFMA(kfa1, qh0, zf);
        f4 s11 = MFMA(kfa1, qh1, zf);
        f4 s12 = MFMA(kfa1, qh2, zf);
        kfa0 = *(const bh8*)(Khi + (size_t)(kna + l16) * DH + quad * 8);
        kfa1 = *(const bh8*)(Khi + (size_t)(kna + 16 + l16) * DH + quad * 8);

        // ---- EARLY next-V prefetch (r16 change: ~800 cyc lead vs ~200) ----
        const bh8 nva0 = *(const bh8*)(Vt + (size_t)(tile0 + 2 * tn) * 1024 + l16 * 32 + quad * 8);
        const bh8 nva1 = *(const bh8*)(Vt + (size_t)(tile0 + 2 * tn) * 1024 + (16 + l16) * 32 + quad * 8);
        const bh8 nvb0 = *(const bh8*)(Vt + (size_t)(tile0 + 2 * tn + 1) * 1024 + l16 * 32 + quad * 8);
        const bh8 nvb1 = *(const bh8*)(Vt + (size_t)(tile0 + 2 * tn + 1) * 1024 + (16 + l16) * 32 + quad * 8);

        // ---- exp A + write P_A ----
        uint4 w0, w1, w2;
        {
            float a = fexp2(s00[0]), b = fexp2(s00[1]),
                  c = fexp2(s00[2]), d = fexp2(s00[3]);
            ls0 += (a + b) + (c + d);
            w0.x = pkbf(a, b); w0.y = pkbf(c, d);
            a = fexp2(s10[0]); b = fexp2(s10[1]);
            c = fexp2(s10[2]); d = fexp2(s10[3]);
            ls0 += (a + b) + (c + d);
            w0.z = pkbf(a, b); w0.w = pkbf(c, d);
            a = fexp2(s01[0]); b = fexp2(s01[1]);
            c = fexp2(s01[2]); d = fexp2(s01[3]);
            ls1 += (a + b) + (c + d);
            w1.x = pkbf(a, b); w1.y = pkbf(c, d);
            a = fexp2(s11[0]); b = fexp2(s11[1]);
            c = fexp2(s11[2]); d = fexp2(s11[3]);
            ls1 += (a + b) + (c + d);
            w1.z = pkbf(a, b); w1.w = pkbf(c, d);
            a = fexp2(s02[0]); b = fexp2(s02[1]);
            c = fexp2(s02[2]); d = fexp2(s02[3]);
            ls2 += (a + b) + (c + d);
            w2.x = pkbf(a, b); w2.y = pkbf(c, d);
            a = fexp2(s12[0]); b = fexp2(s12[1]);
            c = fexp2(s12[2]); d = fexp2(s12[3]);
            ls2 += (a + b) + (c + d);
            w2.z = pkbf(a, b); w2.w = pkbf(c, d);
        }
        *(uint4*)(psw + l16 * PSTR + quad * 8) = w0;
        *(uint4*)(psw + (16 + l16) * PSTR + quad * 8) = w1;
        *(uint4*)(psw + (32 + l16) * PSTR + quad * 8) = w2;

        // ---- QK subtile b (hides writeA->readA latency) ----
        f4 b00 = MFMA(kfb0, qh0, zf);
        f4 b01 = MFMA(kfb0, qh1, zf);
        f4 b02 = MFMA(kfb0, qh2, zf);
        f4 b10 = MFMA(kfb1, qh0, zf);
        f4 b11 = MFMA(kfb1, qh1, zf);
        f4 b12 = MFMA(kfb1, qh2, zf);
        kfb0 = *(const bh8*)(Khi + (size_t)(kna + 32 + l16) * DH + quad * 8);
        kfb1 = *(const bh8*)(Khi + (size_t)(kna + 48 + l16) * DH + quad * 8);

        // ---- exp B (P_B stays in regs until P_A consumed) ----
        uint4 u0, u1, u2;
        {
            float a = fexp2(b00[0]), b = fexp2(b00[1]),
                  c = fexp2(b00[2]), d = fexp2(b00[3]);
            ls0 += (a + b) + (c + d);
            u0.x = pkbf(a, b); u0.y = pkbf(c, d);
            a = fexp2(b10[0]); b = fexp2(b10[1]);
            c = fexp2(b10[2]); d = fexp2(b10[3]);
            ls0 += (a + b) + (c + d);
            u0.z = pkbf(a, b); u0.w = pkbf(c, d);
            a = fexp2(b01[0]); b = fexp2(b01[1]);
            c = fexp2(b01[2]); d = fexp2(b01[3]);
            ls1 += (a + b) + (c + d);
            u1.x = pkbf(a, b); u1.y = pkbf(c, d);
            a = fexp2(b11[0]); b = fexp2(b11[1]);
            c = fexp2(b11[2]); d = fexp2(b11[3]);
            ls1 += (a + b) + (c + d);
            u1.z = pkbf(a, b); u1.w = pkbf(c, d);
            a = fexp2(b02[0]); b = fexp2(b02[1]);
            c = fexp2(b02[2]); d = fexp2(b02[3]);
            ls2 += (a + b) + (c + d);
            u2.x = pkbf(a, b); u2.y = pkbf(c, d);
            a = fexp2(b12[0]); b = fexp2(b12[1]);
            c = fexp2(b12[2]); d = fexp2(b12[3]);
            ls2 += (a + b) + (c + d);
            u2.z = pkbf(a, b); u2.w = pkbf(c, d);
        }

        // ---- read P_A + PV-a ----
        {
            const bh8 pa0 = *(const bh8*)(psw + l16 * PSTR + quad * 8);
            const bh8 pa1 = *(const bh8*)(psw + (16 + l16) * PSTR + quad * 8);
            const bh8 pa2 = *(const bh8*)(psw + (32 + l16) * PSTR + quad * 8);
            o00 = MFMA(pa0, vfa0, o00); o01 = MFMA(pa0, vfa1, o01);
            o10 = MFMA(pa1, vfa0, o10); o11 = MFMA(pa1, vfa1, o11);
            o20 = MFMA(pa2, vfa0, o20); o21 = MFMA(pa2, vfa1, o21);
        }

        // ---- write P_B (after readA issued: per-wave DS in-order => safe) ----
        *(uint4*)(psw + l16 * PSTR + quad * 8) = u0;
        *(uint4*)(psw + (16 + l16) * PSTR + quad * 8) = u1;
        *(uint4*)(psw + (32 + l16) * PSTR + quad * 8) = u2;

        // ---- read P_B + PV-b (latency hidden under PV-a MFMAs) ----
        {
            const bh8 pb0 = *(const bh8*)(psw + l16 * PSTR + quad * 8);
            const bh8 pb1 = *(const bh8*)(psw + (16 + l16) * PSTR + quad * 8);
            const bh8 pb2 = *(const bh8*)(psw + (32 + l16) * PSTR + quad * 8);
            o00 = MFMA(pb0, vfb0, o00); o01 = MFMA(pb0, vfb1, o01);
            o10 = MFMA(pb1, vfb0, o10); o11 = MFMA(pb1, vfb1, o11);
            o20 = MFMA(pb2, vfb0, o20); o21 = MFMA(pb2, vfb1, o21);
        }

        // rotate prefetched V in
        vfa0 = nva0; vfa1 = nva1; vfb0 = nvb0; vfb1 = nvb1;
    }

    // per-wave row sums: reduce across quads (this wave's full key range)
    ls0 += __shfl_xor(ls0, 16); ls0 += __shfl_xor(ls0, 32);
    ls1 += __shfl_xor(ls1, 16); ls1 += __shfl_xor(ls1, 32);
    ls2 += __shfl_xor(ls2, 16); ls2 += __shfl_xor(ls2, 32);

    // two-stage additive merge: waves 0..7 write planes, waves 8..15 add in
    __syncthreads();
    float* mo = (float*)shm;                 // [8][32*48] = 49.2 KB
    float* mls = mo + 8 * 1536;              // [8][48]
    const int mw = wave & 7;
    float* mp = mo + mw * 1536;
    if (wave < 8) {
        #pragma unroll
        for (int reg = 0; reg < 4; ++reg) {
            const int q0 = quad * 4 + reg;
            mp[l16 * 48 + q0]             = o00[reg];
            mp[(16 + l16) * 48 + q0]      = o01[reg];
            mp[l16 * 48 + 16 + q0]        = o10[reg];
            mp[(16 + l16) * 48 + 16 + q0] = o11[reg];
            mp[l16 * 48 + 32 + q0]        = o20[reg];
            mp[(16 + l16) * 48 + 32 + q0] = o21[reg];
        }
        if (quad == 0) {
            mls[mw * 48 + l16]      = ls0;
            mls[mw * 48 + 16 + l16] = ls1;
            mls[mw * 48 + 32 + l16] = ls2;
        }
    }
    __syncthreads();
    if (wave >= 8) {
        #pragma unroll
        for (int reg = 0; reg < 4; ++reg) {
            const int q0 = quad * 4 + reg;
            mp[l16 * 48 + q0]             += o00[reg];
            mp[(16 + l16) * 48 + q0]      += o01[reg];
            mp[l16 * 48 + 16 + q0]        += o10[reg];
            mp[(16 + l16) * 48 + 16 + q0] += o11[reg];
            mp[l16 * 48 + 32 + q0]        += o20[reg];
            mp[(16 + l16) * 48 + 32 + q0] += o21[reg];
        }
        if (quad == 0) {
            mls[mw * 48 + l16]      += ls0;
            mls[mw * 48 + 16 + l16] += ls1;
            mls[mw * 48 + 32 + l16] += ls2;
        }
    }
    __syncthreads();

    const int bg = n0 / LSP;
    const int l0 = n0 - bg * LSP;
    for (int c = t; c < 32 * QB; c += 1024) {
        const int d = c / QB;
        const int q = c - d * QB;
        float num = 0.f, den = 0.f;
        #pragma unroll
        for (int w2 = 0; w2 < 8; ++w2) {
            num += mo[w2 * 1536 + d * 48 + q];
            den += mls[w2 * 48 + q];
        }
        out[((size_t)(bg * 32 + d)) * LSP + l0 + q] = num / den;
    }
}

extern "C" void kernel_launch(void* const* d_in, const int* in_sizes, int n_in,
                              void* d_out, int out_size, void* d_ws, size_t ws_size,
                              hipStream_t stream) {
    (void)in_sizes; (void)n_in; (void)out_size; (void)ws_size;
    const float* x  = (const float*)d_in[0];
    const float* wq = (const float*)d_in[1];
    const float* wk = (const float*)d_in[2];
    const float* wv = (const float*)d_in[3];

    unsigned short* ws = (unsigned short*)d_ws;
    unsigned short* Qhi = ws;
    unsigned short* Khi = ws + SZP;
    unsigned short* Vt  = ws + 2 * SZP;
    float* out = (float*)d_out;

    sa_proj_kernel<<<256, 256, 0, stream>>>(x, wq, wk, wv, Qhi, Khi, Vt);
    sa_attn_kernel<<<256, 1024, 0, stream>>>(Qhi, Khi, Vt, out);
}